// Round 3
// baseline (726.786 us; speedup 1.0000x reference)
//
#include <hip/hip_runtime.h>

#define NMEM 16384
#define MDIM 225
#define L1D 134
#define MCLS 4489     // 67*67 real positions per class
#define PPAD 4608     // 144*32 padded positions
#define NTILE 512     // 32-n tiles
#define MARGIN 0.05f

typedef __attribute__((ext_vector_type(8))) short bf16x8;
typedef __attribute__((ext_vector_type(16))) float f32x16;

__device__ inline unsigned short f2bf(float f) {
    unsigned u = __float_as_uint(f);
    return (unsigned short)((u + 0x7FFFu + ((u >> 16) & 1u)) >> 16);
}
__device__ inline float bf2f(unsigned short h) {
    return __uint_as_float(((unsigned)h) << 16);
}

// ---------------------------------------------------------------------------
// P0: collapsed filters, elementwise: one thread per (cls, n, k). Each output
// is the sum of <=4 source taps. Layout cm[(cls*NMEM+n)*64+k] == gid.
// ---------------------------------------------------------------------------
__global__ __launch_bounds__(256) void prep_cm(const float* __restrict__ mem,
                                               unsigned short* __restrict__ cmh,
                                               unsigned short* __restrict__ cml) {
    const int gid = blockIdx.x * 256 + threadIdx.x;   // 4*16384*64 = 2^22
    const int k = gid & 63, n = (gid >> 6) & (NMEM - 1), cls = gid >> 20;
    const int u = k >> 3, v = k & 7, er = cls >> 1, ec = cls & 1;
    const int i0 = 2 * u - er, j0 = 2 * v - ec;
    const float* mrow = mem + (size_t)n * MDIM;
    float s = 0.f;
    #pragma unroll
    for (int di = 0; di < 2; ++di) {
        const int i = i0 + di;
        if ((unsigned)i >= 15u) continue;
        #pragma unroll
        for (int dj = 0; dj < 2; ++dj) {
            const int j = j0 + dj;
            if ((unsigned)j >= 15u) continue;
            s += mrow[i * 15 + j];
        }
    }
    const unsigned short h = f2bf(s);
    cmh[gid] = h;
    cml[gid] = f2bf(s - bf2f(h));
}

// ---------------------------------------------------------------------------
// P1: hn[n] = 0.5*||mem_n||^2, one wave per n.
// ---------------------------------------------------------------------------
__global__ __launch_bounds__(256) void prep_hn(const float* __restrict__ mem,
                                               float* __restrict__ hn) {
    const int wave = threadIdx.x >> 6, lane = threadIdx.x & 63;
    const int n = blockIdx.x * 4 + wave;
    const float* mrow = mem + (size_t)n * MDIM;
    float s = 0.f;
    for (int t = lane; t < MDIM; t += 64) { const float v = mrow[t]; s += v * v; }
    #pragma unroll
    for (int m = 1; m < 64; m <<= 1) s += __shfl_xor(s, m);
    if (lane == 0) hn[n] = 0.5f * s;
}

// ---------------------------------------------------------------------------
// P2: X (positions) in B-fragment layout: x[(ptile*4+ks)*2+g][lane32][8j],
// hi/lo bf16. pos = ptile*32+nl, k = ks*16+g*8+j, u=k>>3 (const/thread), v=j.
// ---------------------------------------------------------------------------
__global__ __launch_bounds__(256) void prep_x(const float* __restrict__ img,
                                              unsigned short* __restrict__ xh,
                                              unsigned short* __restrict__ xl) {
    const int t = blockIdx.x * 256 + threadIdx.x;   // 144*4*2*32 = 36864
    const int nl = t & 31, g = (t >> 5) & 1, ks = (t >> 6) & 3, pt = t >> 8;
    const int pos = pt * 32 + nl;
    const int u = ks * 2 + g;
    bf16x8 h, l;
    if (pos < MCLS) {
        const int mr = pos / 67, mc = pos - mr * 67;
        const int r = mr - 5 + u;
        #pragma unroll
        for (int j = 0; j < 8; ++j) {
            const int c = mc - 5 + j;
            float v = 0.f;
            if ((unsigned)r < 64u && (unsigned)c < 64u) v = img[r * 64 + c];
            const unsigned short hb = f2bf(v);
            h[j] = (short)hb;
            l[j] = (short)f2bf(v - bf2f(hb));
        }
    } else {
        #pragma unroll
        for (int j = 0; j < 8; ++j) { h[j] = 0; l[j] = 0; }
    }
    *(bf16x8*)(xh + (size_t)t * 8) = h;
    *(bf16x8*)(xl + (size_t)t * 8) = l;
}

// ---------------------------------------------------------------------------
// K1: transposed MFMA scoring. Grid (256 nblk, 4 cls), 256 thr = 4 waves.
// A = mem (64 n-rows, register-resident hi/lo), B = X frags (coalesced 1 KB
// loads per frag). No LDS, no barriers. Per iter: wave covers 2 position
// tiles (cg) x 64 n; epilogue = in-lane tree-max over 16 rows per rg (packed
// value|5-bit row id), cross-g shfl, coalesced store of top-1 per 32-n tile.
// A-frag: m=lane&31, k=g*8+j (+16*ks). B-frag: n=lane&31, k=g*8+j.
// C/D: col=lane&31 (position), row=(r&3)+8*(r>>2)+4*g (n-local) [verified].
// ---------------------------------------------------------------------------
__global__ __launch_bounds__(256) void mfma_argmin_kernel(const unsigned short* __restrict__ cmh,
                                                          const unsigned short* __restrict__ cml,
                                                          const unsigned short* __restrict__ xh,
                                                          const unsigned short* __restrict__ xl,
                                                          const float* __restrict__ hn,
                                                          float* __restrict__ pcv) {
    const int nblk = blockIdx.x, cls = blockIdx.y;
    const int t = threadIdx.x, wave = t >> 6, lane = t & 63;
    const int g = lane >> 5, nl = lane & 31;

    bf16x8 ah[2][4], al[2][4];
    #pragma unroll
    for (int rg = 0; rg < 2; ++rg)
        #pragma unroll
        for (int ks = 0; ks < 4; ++ks) {
            const size_t base = ((size_t)(cls * NMEM + nblk * 64 + rg * 32 + nl)) * 64 + ks * 16 + g * 8;
            ah[rg][ks] = *(const bf16x8*)(cmh + base);
            al[rg][ks] = *(const bf16x8*)(cml + base);
        }

    float hnv[2][16];
    #pragma unroll
    for (int rg = 0; rg < 2; ++rg)
        #pragma unroll
        for (int r = 0; r < 16; ++r)
            hnv[rg][r] = hn[nblk * 64 + rg * 32 + (r & 3) + 8 * (r >> 2) + 4 * g];

    const size_t obase = (size_t)(cls * NTILE + nblk * 2) * PPAD;

    for (int it = 0; it < 18; ++it) {
        const int pt0 = it * 8 + wave * 2;
        bf16x8 bh[2][4], bl[2][4];
        #pragma unroll
        for (int cg = 0; cg < 2; ++cg)
            #pragma unroll
            for (int ks = 0; ks < 4; ++ks) {
                const size_t xo = ((size_t)(((pt0 + cg) * 4 + ks) * 2 + g)) * 256 + nl * 8;
                bh[cg][ks] = *(const bf16x8*)(xh + xo);
                bl[cg][ks] = *(const bf16x8*)(xl + xo);
            }

        f32x16 acc[2][2];
        #pragma unroll
        for (int rg = 0; rg < 2; ++rg)
            #pragma unroll
            for (int cg = 0; cg < 2; ++cg)
                #pragma unroll
                for (int r = 0; r < 16; ++r) acc[rg][cg][r] = 0.f;

        #pragma unroll
        for (int ks = 0; ks < 4; ++ks)
            #pragma unroll
            for (int cg = 0; cg < 2; ++cg)
                #pragma unroll
                for (int rg = 0; rg < 2; ++rg) {
                    acc[rg][cg] = __builtin_amdgcn_mfma_f32_32x32x16_bf16(ah[rg][ks], bh[cg][ks], acc[rg][cg], 0, 0, 0);
                    acc[rg][cg] = __builtin_amdgcn_mfma_f32_32x32x16_bf16(al[rg][ks], bh[cg][ks], acc[rg][cg], 0, 0, 0);
                    acc[rg][cg] = __builtin_amdgcn_mfma_f32_32x32x16_bf16(ah[rg][ks], bl[cg][ks], acc[rg][cg], 0, 0, 0);
                }

        // Epilogue: packed (score | 5-bit row id), tree-max per rg, cross-g.
        float pm[2][2];   // [cg][rg]
        #pragma unroll
        for (int cg = 0; cg < 2; ++cg)
            #pragma unroll
            for (int rg = 0; rg < 2; ++rg) {
                float mm = -3.0e38f;
                #pragma unroll
                for (int r = 0; r < 16; ++r) {
                    const float s = acc[rg][cg][r] - hnv[rg][r];
                    const int id = (r & 3) + 8 * (r >> 2) + 4 * g;
                    const float p = __int_as_float((__float_as_int(s) & ~31) | id);
                    mm = fmaxf(mm, p);
                }
                pm[cg][rg] = mm;
            }
        #pragma unroll
        for (int cg = 0; cg < 2; ++cg)
            #pragma unroll
            for (int rg = 0; rg < 2; ++rg)
                pm[cg][rg] = fmaxf(pm[cg][rg], __shfl_xor(pm[cg][rg], 32));

        // g=0 lanes store cg0's results, g=1 lanes store cg1's.
        const int pos = (pt0 + g) * 32 + nl;
        const float q0 = g ? pm[1][0] : pm[0][0];
        const float q1 = g ? pm[1][1] : pm[0][1];
        pcv[obase + pos] = q0;
        pcv[obase + PPAD + pos] = q1;
    }
}

// ---------------------------------------------------------------------------
// K2: scan 512 tile-maxes per (cls,pos), exact-rescore candidates within
// MARGIN directly from mem, write idx2d.
// ---------------------------------------------------------------------------
template<int ER, int EC>
__device__ float exact_score(const float* __restrict__ mrow, const float* __restrict__ x) {
    float s = 0.f;
    #pragma unroll
    for (int i = 0; i < 15; ++i) {
        const int u = (i + ER) >> 1;
        #pragma unroll
        for (int j = 0; j < 15; ++j) {
            const int v = (j + EC) >> 1;
            s = fmaf(mrow[i * 15 + j], x[u * 8 + v], s);
        }
    }
    return s;
}

__global__ __launch_bounds__(256) void rescue_kernel(const float* __restrict__ img,
                                                     const float* __restrict__ mem,
                                                     const float* __restrict__ hn,
                                                     const float* __restrict__ pcv,
                                                     int* __restrict__ idx2d) {
    const int m = blockIdx.x * 256 + threadIdx.x;
    const int cls = blockIdx.y;
    if (m >= MCLS) return;
    const float* col = pcv + (size_t)cls * NTILE * PPAD + m;

    float vmax = -3.0e38f;
    for (int nt = 0; nt < NTILE; ++nt) vmax = fmaxf(vmax, col[(size_t)nt * PPAD]);
    const float thr = vmax - MARGIN;

    const int mr = m / 67, mc = m - mr * 67;
    float x[64];
    #pragma unroll
    for (int u = 0; u < 8; ++u)
        #pragma unroll
        for (int v = 0; v < 8; ++v) {
            const int r = mr - 5 + u, c = mc - 5 + v;
            x[u * 8 + v] = ((unsigned)r < 64u && (unsigned)c < 64u) ? img[r * 64 + c] : 0.f;
        }

    float best = -3.0e38f; int bn = 0x7FFFFFFF;
    for (int nt = 0; nt < NTILE; ++nt) {
        const float v = col[(size_t)nt * PPAD];
        if (v < thr) continue;
        const int n = nt * 32 + (__float_as_int(v) & 31);
        const float* mrow = mem + (size_t)n * MDIM;
        float s;
        if (cls == 0)      s = exact_score<0, 0>(mrow, x);
        else if (cls == 1) s = exact_score<0, 1>(mrow, x);
        else if (cls == 2) s = exact_score<1, 0>(mrow, x);
        else               s = exact_score<1, 1>(mrow, x);
        s -= hn[n];
        if (s > best || (s == best && n < bn)) { best = s; bn = n; }
    }
    const int er = cls >> 1, ec = cls & 1;
    idx2d[(er + 2 * mr) * L1D + (ec + 2 * mc)] = bn;
}

// ---------------------------------------------------------------------------
// K3: fold, one wave per output pixel (latency-parallel gathers + shfl reduce).
// ---------------------------------------------------------------------------
__global__ __launch_bounds__(256) void fold_kernel(const float* __restrict__ mem,
                                                   const int* __restrict__ idx2d,
                                                   float* __restrict__ outraw) {
    const int wave = threadIdx.x >> 6, lane = threadIdx.x & 63;
    const int p = blockIdx.x * 4 + wave;   // 0..4095
    const int oi = p >> 6, oj = p & 63;
    float s = 0.f;
    #pragma unroll
    for (int tb = 0; tb < 256; tb += 64) {
        const int tt = tb + lane;
        if (tt < MDIM) {
            const int a = tt / 15, b = tt - 15 * a;
            const int r = 10 + 2 * oi - a, c = 10 + 2 * oj - b;
            if ((unsigned)r < (unsigned)L1D && (unsigned)c < (unsigned)L1D) {
                const int n = idx2d[r * L1D + c];
                s += mem[(size_t)n * MDIM + tt];
            }
        }
    }
    #pragma unroll
    for (int msk = 1; msk < 64; msk <<= 1) s += __shfl_xor(s, msk);
    if (lane == 0) outraw[p] = s;
}

// ---------------------------------------------------------------------------
// K4: divide by global max (single block).
// ---------------------------------------------------------------------------
__global__ __launch_bounds__(256) void norm_kernel(const float* __restrict__ outraw,
                                                   float* __restrict__ out) {
    __shared__ float red[256];
    const int t = threadIdx.x;
    float m = -3.0e38f;
    #pragma unroll
    for (int i = 0; i < 16; ++i) m = fmaxf(m, outraw[t + i * 256]);
    red[t] = m;
    __syncthreads();
    for (int s = 128; s > 0; s >>= 1) {
        if (t < s) red[t] = fmaxf(red[t], red[t + s]);
        __syncthreads();
    }
    const float mx = red[0];
    #pragma unroll
    for (int i = 0; i < 16; ++i) out[t + i * 256] = outraw[t + i * 256] / mx;
}

extern "C" void kernel_launch(void* const* d_in, const int* in_sizes, int n_in,
                              void* d_out, int out_size, void* d_ws, size_t ws_size,
                              hipStream_t stream) {
    const float* img = (const float*)d_in[0];   // 64*64 fp32
    const float* mem = (const float*)d_in[1];   // 16384*225 fp32
    float* out = (float*)d_out;                 // 4096 fp32

    unsigned short* cmh = (unsigned short*)d_ws;              // 4*16384*64 shorts
    unsigned short* cml = cmh + (size_t)4 * NMEM * 64;
    float* hn = (float*)(cml + (size_t)4 * NMEM * 64);        // 16384 f
    unsigned short* xh = (unsigned short*)(hn + NMEM);        // 144*4*2*256 = 294912 shorts
    unsigned short* xl = xh + 294912;
    float* pcv = (float*)(xl + 294912);                       // 4*512*4608 f = 37.7 MB
    int* idx2d = (int*)(pcv + (size_t)4 * NTILE * PPAD);      // 17956 i
    float* outraw = (float*)(idx2d + L1D * L1D);              // 4096 f
    // total ~56 MB of ws

    prep_cm<<<(4 * NMEM * 64) / 256, 256, 0, stream>>>(mem, cmh, cml);
    prep_hn<<<NMEM / 4, 256, 0, stream>>>(mem, hn);
    prep_x<<<144, 256, 0, stream>>>(img, xh, xl);
    mfma_argmin_kernel<<<dim3(256, 4), 256, 0, stream>>>(cmh, cml, xh, xl, hn, pcv);
    rescue_kernel<<<dim3(18, 4), 256, 0, stream>>>(img, mem, hn, pcv, idx2d);
    fold_kernel<<<1024, 256, 0, stream>>>(mem, idx2d, outraw);
    norm_kernel<<<1, 256, 0, stream>>>(outraw, out);
}

// Round 4
// 268.836 us; speedup vs baseline: 2.7035x; 2.7035x over previous
//
#include <hip/hip_runtime.h>

#define NMEM 16384
#define MDIM 225
#define L1D 134
#define MCLS 4489     // 67*67 real positions per class
#define PPAD 4608     // 144*32 padded positions
#define NTILE 512     // 32-n tiles
#define MARGIN 0.05f

typedef __attribute__((ext_vector_type(8))) short bf16x8;
typedef __attribute__((ext_vector_type(16))) float f32x16;

__device__ inline unsigned short f2bf(float f) {
    unsigned u = __float_as_uint(f);
    return (unsigned short)((u + 0x7FFFu + ((u >> 16) & 1u)) >> 16);
}
__device__ inline float bf2f(unsigned short h) {
    return __uint_as_float(((unsigned)h) << 16);
}

// ---------------------------------------------------------------------------
// P0: collapsed filters, elementwise: one thread per (cls, n, k). Each output
// is the sum of <=4 source taps. Layout cm[(cls*NMEM+n)*64+k] == gid.
// ---------------------------------------------------------------------------
__global__ __launch_bounds__(256) void prep_cm(const float* __restrict__ mem,
                                               unsigned short* __restrict__ cmh,
                                               unsigned short* __restrict__ cml) {
    const int gid = blockIdx.x * 256 + threadIdx.x;   // 4*16384*64 = 2^22
    const int k = gid & 63, n = (gid >> 6) & (NMEM - 1), cls = gid >> 20;
    const int u = k >> 3, v = k & 7, er = cls >> 1, ec = cls & 1;
    const int i0 = 2 * u - er, j0 = 2 * v - ec;
    const float* mrow = mem + (size_t)n * MDIM;
    float s = 0.f;
    #pragma unroll
    for (int di = 0; di < 2; ++di) {
        const int i = i0 + di;
        if ((unsigned)i >= 15u) continue;
        #pragma unroll
        for (int dj = 0; dj < 2; ++dj) {
            const int j = j0 + dj;
            if ((unsigned)j >= 15u) continue;
            s += mrow[i * 15 + j];
        }
    }
    const unsigned short h = f2bf(s);
    cmh[gid] = h;
    cml[gid] = f2bf(s - bf2f(h));
}

// ---------------------------------------------------------------------------
// P1: hn[n] = 0.5*||mem_n||^2, one wave per n.
// ---------------------------------------------------------------------------
__global__ __launch_bounds__(256) void prep_hn(const float* __restrict__ mem,
                                               float* __restrict__ hn) {
    const int wave = threadIdx.x >> 6, lane = threadIdx.x & 63;
    const int n = blockIdx.x * 4 + wave;
    const float* mrow = mem + (size_t)n * MDIM;
    float s = 0.f;
    for (int t = lane; t < MDIM; t += 64) { const float v = mrow[t]; s += v * v; }
    #pragma unroll
    for (int m = 1; m < 64; m <<= 1) s += __shfl_xor(s, m);
    if (lane == 0) hn[n] = 0.5f * s;
}

// ---------------------------------------------------------------------------
// P2: X (positions) in B-fragment layout: x[(ptile*4+ks)*2+g][lane32][8j],
// hi/lo bf16. pos = ptile*32+nl, k = ks*16+g*8+j, u=k>>3 (const/thread), v=j.
// ---------------------------------------------------------------------------
__global__ __launch_bounds__(256) void prep_x(const float* __restrict__ img,
                                              unsigned short* __restrict__ xh,
                                              unsigned short* __restrict__ xl) {
    const int t = blockIdx.x * 256 + threadIdx.x;   // 144*4*2*32 = 36864
    const int nl = t & 31, g = (t >> 5) & 1, ks = (t >> 6) & 3, pt = t >> 8;
    const int pos = pt * 32 + nl;
    const int u = ks * 2 + g;
    bf16x8 h, l;
    if (pos < MCLS) {
        const int mr = pos / 67, mc = pos - mr * 67;
        const int r = mr - 5 + u;
        #pragma unroll
        for (int j = 0; j < 8; ++j) {
            const int c = mc - 5 + j;
            float v = 0.f;
            if ((unsigned)r < 64u && (unsigned)c < 64u) v = img[r * 64 + c];
            const unsigned short hb = f2bf(v);
            h[j] = (short)hb;
            l[j] = (short)f2bf(v - bf2f(hb));
        }
    } else {
        #pragma unroll
        for (int j = 0; j < 8; ++j) { h[j] = 0; l[j] = 0; }
    }
    *(bf16x8*)(xh + (size_t)t * 8) = h;
    *(bf16x8*)(xl + (size_t)t * 8) = l;
}

// ---------------------------------------------------------------------------
// K1: transposed MFMA scoring (verified in R3, unchanged).
// A-frag: m=lane&31, k=g*8+j (+16*ks). B-frag: n=lane&31, k=g*8+j.
// C/D: col=lane&31 (position), row=(r&3)+8*(r>>2)+4*g (n-local).
// ---------------------------------------------------------------------------
__global__ __launch_bounds__(256) void mfma_argmin_kernel(const unsigned short* __restrict__ cmh,
                                                          const unsigned short* __restrict__ cml,
                                                          const unsigned short* __restrict__ xh,
                                                          const unsigned short* __restrict__ xl,
                                                          const float* __restrict__ hn,
                                                          float* __restrict__ pcv) {
    const int nblk = blockIdx.x, cls = blockIdx.y;
    const int t = threadIdx.x, wave = t >> 6, lane = t & 63;
    const int g = lane >> 5, nl = lane & 31;

    bf16x8 ah[2][4], al[2][4];
    #pragma unroll
    for (int rg = 0; rg < 2; ++rg)
        #pragma unroll
        for (int ks = 0; ks < 4; ++ks) {
            const size_t base = ((size_t)(cls * NMEM + nblk * 64 + rg * 32 + nl)) * 64 + ks * 16 + g * 8;
            ah[rg][ks] = *(const bf16x8*)(cmh + base);
            al[rg][ks] = *(const bf16x8*)(cml + base);
        }

    float hnv[2][16];
    #pragma unroll
    for (int rg = 0; rg < 2; ++rg)
        #pragma unroll
        for (int r = 0; r < 16; ++r)
            hnv[rg][r] = hn[nblk * 64 + rg * 32 + (r & 3) + 8 * (r >> 2) + 4 * g];

    const size_t obase = (size_t)(cls * NTILE + nblk * 2) * PPAD;

    for (int it = 0; it < 18; ++it) {
        const int pt0 = it * 8 + wave * 2;
        bf16x8 bh[2][4], bl[2][4];
        #pragma unroll
        for (int cg = 0; cg < 2; ++cg)
            #pragma unroll
            for (int ks = 0; ks < 4; ++ks) {
                const size_t xo = ((size_t)(((pt0 + cg) * 4 + ks) * 2 + g)) * 256 + nl * 8;
                bh[cg][ks] = *(const bf16x8*)(xh + xo);
                bl[cg][ks] = *(const bf16x8*)(xl + xo);
            }

        f32x16 acc[2][2];
        #pragma unroll
        for (int rg = 0; rg < 2; ++rg)
            #pragma unroll
            for (int cg = 0; cg < 2; ++cg)
                #pragma unroll
                for (int r = 0; r < 16; ++r) acc[rg][cg][r] = 0.f;

        #pragma unroll
        for (int ks = 0; ks < 4; ++ks)
            #pragma unroll
            for (int cg = 0; cg < 2; ++cg)
                #pragma unroll
                for (int rg = 0; rg < 2; ++rg) {
                    acc[rg][cg] = __builtin_amdgcn_mfma_f32_32x32x16_bf16(ah[rg][ks], bh[cg][ks], acc[rg][cg], 0, 0, 0);
                    acc[rg][cg] = __builtin_amdgcn_mfma_f32_32x32x16_bf16(al[rg][ks], bh[cg][ks], acc[rg][cg], 0, 0, 0);
                    acc[rg][cg] = __builtin_amdgcn_mfma_f32_32x32x16_bf16(ah[rg][ks], bl[cg][ks], acc[rg][cg], 0, 0, 0);
                }

        float pm[2][2];   // [cg][rg]
        #pragma unroll
        for (int cg = 0; cg < 2; ++cg)
            #pragma unroll
            for (int rg = 0; rg < 2; ++rg) {
                float mm = -3.0e38f;
                #pragma unroll
                for (int r = 0; r < 16; ++r) {
                    const float s = acc[rg][cg][r] - hnv[rg][r];
                    const int id = (r & 3) + 8 * (r >> 2) + 4 * g;
                    const float p = __int_as_float((__float_as_int(s) & ~31) | id);
                    mm = fmaxf(mm, p);
                }
                pm[cg][rg] = mm;
            }
        #pragma unroll
        for (int cg = 0; cg < 2; ++cg)
            #pragma unroll
            for (int rg = 0; rg < 2; ++rg)
                pm[cg][rg] = fmaxf(pm[cg][rg], __shfl_xor(pm[cg][rg], 32));

        const int pos = (pt0 + g) * 32 + nl;
        const float q0 = g ? pm[1][0] : pm[0][0];
        const float q1 = g ? pm[1][1] : pm[0][1];
        pcv[obase + pos] = q0;
        pcv[obase + PPAD + pos] = q1;
    }
}

// ---------------------------------------------------------------------------
// T: transpose pcv (4, NTILE, PPAD) -> pcvT (4, PPAD, NTILE) via 64x64 LDS
// tiles, both sides fully coalesced. Grid (PPAD/64, NTILE/64, 4).
// ---------------------------------------------------------------------------
__global__ __launch_bounds__(256) void transpose_kernel(const float* __restrict__ in,
                                                        float* __restrict__ out) {
    __shared__ float tile[64][65];
    const int pb = blockIdx.x, tb = blockIdx.y, cls = blockIdx.z;
    const int tx = threadIdx.x & 63, ty = threadIdx.x >> 6;
    const size_t ibase = ((size_t)(cls * NTILE + tb * 64)) * PPAD + pb * 64;
    #pragma unroll
    for (int r = 0; r < 16; ++r) {
        const int i = ty + r * 4;
        tile[i][tx] = in[ibase + (size_t)i * PPAD + tx];
    }
    __syncthreads();
    const size_t obase = ((size_t)(cls * PPAD + pb * 64)) * NTILE + tb * 64;
    #pragma unroll
    for (int r = 0; r < 16; ++r) {
        const int p = ty + r * 4;
        out[obase + (size_t)p * NTILE + tx] = tile[tx][p];
    }
}

// ---------------------------------------------------------------------------
// K2: rescue, one wave per (cls, pos). Coalesced read of 512 tile-maxes,
// shfl-max -> vmax, ballot candidates within MARGIN, wave-cooperative exact
// rescore (4 coalesced mem taps/lane + shfl reduce). Tie rule: (s>best) ||
// (s==best && n<bn) — order-independent, matches argmin-first.
// ---------------------------------------------------------------------------
__global__ __launch_bounds__(256) void rescue_kernel(const float* __restrict__ img,
                                                     const float* __restrict__ mem,
                                                     const float* __restrict__ hn,
                                                     const float* __restrict__ pcvT,
                                                     int* __restrict__ idx2d) {
    const int wave = threadIdx.x >> 6, lane = threadIdx.x & 63;
    const int cls = blockIdx.y;
    const int pos = blockIdx.x * 4 + wave;
    if (pos >= MCLS) return;
    const int er = cls >> 1, ec = cls & 1;
    const int mr = pos / 67, mc = pos - mr * 67;

    // per-lane x value: x[lane] = img[mr-5+(lane>>3)][mc-5+(lane&7)] (0 OOB)
    {
    }
    const int xr = mr - 5 + (lane >> 3), xc = mc - 5 + (lane & 7);
    const float xv = ((unsigned)xr < 64u && (unsigned)xc < 64u) ? img[xr * 64 + xc] : 0.f;

    // per-lane taps tt = q*64+lane: fetch the x value each tap needs (bpermute)
    float xt[4];
    #pragma unroll
    for (int q = 0; q < 4; ++q) {
        const int tt = q * 64 + lane;
        const int a = tt / 15, b = tt - 15 * a;       // a<=16, only tt<225 used
        const int xi = (((a + er) >> 1) & 7) * 8 + (((b + ec) >> 1) & 7);
        xt[q] = __shfl(xv, xi);
    }

    const float* row = pcvT + ((size_t)(cls * PPAD + pos)) * NTILE + lane * 8;
    const float4 v0 = *(const float4*)row;
    const float4 v1 = *(const float4*)(row + 4);
    float vals[8] = {v0.x, v0.y, v0.z, v0.w, v1.x, v1.y, v1.z, v1.w};

    float vmax = vals[0];
    #pragma unroll
    for (int s = 1; s < 8; ++s) vmax = fmaxf(vmax, vals[s]);
    #pragma unroll
    for (int m = 1; m < 64; m <<= 1) vmax = fmaxf(vmax, __shfl_xor(vmax, m));
    const float thr = vmax - MARGIN;

    float best = -3.0e38f; int bn = 0x7FFFFFFF;
    #pragma unroll
    for (int s = 0; s < 8; ++s) {
        unsigned long long bal = __ballot(vals[s] >= thr);
        while (bal) {
            const int src = __ffsll((long long)bal) - 1;
            bal &= bal - 1;
            const float pv = __shfl(vals[s], src);
            const int n = (src * 8 + s) * 32 + (__float_as_int(pv) & 31);
            const float* mrow = mem + (size_t)n * MDIM;
            float part = 0.f;
            #pragma unroll
            for (int q = 0; q < 4; ++q) {
                const int tt = q * 64 + lane;
                if (tt < MDIM) part = fmaf(mrow[tt], xt[q], part);
            }
            #pragma unroll
            for (int m = 1; m < 64; m <<= 1) part += __shfl_xor(part, m);
            const float sc = part - hn[n];
            if (sc > best || (sc == best && n < bn)) { best = sc; bn = n; }
        }
    }
    if (lane == 0) idx2d[(er + 2 * mr) * L1D + (ec + 2 * mc)] = bn;
}

// ---------------------------------------------------------------------------
// K3: fold, one wave per output pixel.
// ---------------------------------------------------------------------------
__global__ __launch_bounds__(256) void fold_kernel(const float* __restrict__ mem,
                                                   const int* __restrict__ idx2d,
                                                   float* __restrict__ outraw) {
    const int wave = threadIdx.x >> 6, lane = threadIdx.x & 63;
    const int p = blockIdx.x * 4 + wave;   // 0..4095
    const int oi = p >> 6, oj = p & 63;
    float s = 0.f;
    #pragma unroll
    for (int tb = 0; tb < 256; tb += 64) {
        const int tt = tb + lane;
        if (tt < MDIM) {
            const int a = tt / 15, b = tt - 15 * a;
            const int r = 10 + 2 * oi - a, c = 10 + 2 * oj - b;
            if ((unsigned)r < (unsigned)L1D && (unsigned)c < (unsigned)L1D) {
                const int n = idx2d[r * L1D + c];
                s += mem[(size_t)n * MDIM + tt];
            }
        }
    }
    #pragma unroll
    for (int msk = 1; msk < 64; msk <<= 1) s += __shfl_xor(s, msk);
    if (lane == 0) outraw[p] = s;
}

// ---------------------------------------------------------------------------
// K4: divide by global max (single block).
// ---------------------------------------------------------------------------
__global__ __launch_bounds__(256) void norm_kernel(const float* __restrict__ outraw,
                                                   float* __restrict__ out) {
    __shared__ float red[256];
    const int t = threadIdx.x;
    float m = -3.0e38f;
    #pragma unroll
    for (int i = 0; i < 16; ++i) m = fmaxf(m, outraw[t + i * 256]);
    red[t] = m;
    __syncthreads();
    for (int s = 128; s > 0; s >>= 1) {
        if (t < s) red[t] = fmaxf(red[t], red[t + s]);
        __syncthreads();
    }
    const float mx = red[0];
    #pragma unroll
    for (int i = 0; i < 16; ++i) out[t + i * 256] = outraw[t + i * 256] / mx;
}

extern "C" void kernel_launch(void* const* d_in, const int* in_sizes, int n_in,
                              void* d_out, int out_size, void* d_ws, size_t ws_size,
                              hipStream_t stream) {
    const float* img = (const float*)d_in[0];   // 64*64 fp32
    const float* mem = (const float*)d_in[1];   // 16384*225 fp32
    float* out = (float*)d_out;                 // 4096 fp32

    unsigned short* cmh = (unsigned short*)d_ws;              // 4*16384*64 shorts
    unsigned short* cml = cmh + (size_t)4 * NMEM * 64;
    float* hn = (float*)(cml + (size_t)4 * NMEM * 64);        // 16384 f
    unsigned short* xh = (unsigned short*)(hn + NMEM);        // 294912 shorts
    unsigned short* xl = xh + 294912;
    float* pcv = (float*)(xl + 294912);                       // 4*512*4608 f = 37.7 MB
    float* pcvT = pcv + (size_t)4 * NTILE * PPAD;             // 37.7 MB
    int* idx2d = (int*)(pcvT + (size_t)4 * NTILE * PPAD);     // 17956 i
    float* outraw = (float*)(idx2d + L1D * L1D);              // 4096 f
    // total ~94 MB of ws

    prep_cm<<<(4 * NMEM * 64) / 256, 256, 0, stream>>>(mem, cmh, cml);
    prep_hn<<<NMEM / 4, 256, 0, stream>>>(mem, hn);
    prep_x<<<144, 256, 0, stream>>>(img, xh, xl);
    mfma_argmin_kernel<<<dim3(256, 4), 256, 0, stream>>>(cmh, cml, xh, xl, hn, pcv);
    transpose_kernel<<<dim3(PPAD / 64, NTILE / 64, 4), 256, 0, stream>>>(pcv, pcvT);
    rescue_kernel<<<dim3((MCLS + 3) / 4, 4), 256, 0, stream>>>(img, mem, hn, pcvT, idx2d);
    fold_kernel<<<1024, 256, 0, stream>>>(mem, idx2d, outraw);
    norm_kernel<<<1, 256, 0, stream>>>(outraw, out);
}

// Round 5
// 233.987 us; speedup vs baseline: 3.1061x; 1.1489x over previous
//
#include <hip/hip_runtime.h>

#define NMEM 16384
#define MDIM 225
#define L1D 134
#define MCLS 4489     // 67*67 real positions per class
#define PPAD 4608     // 144*32 padded positions
#define NTILE 512     // 32-n tiles
#define MARGIN 0.05f

typedef __attribute__((ext_vector_type(8))) short bf16x8;
typedef __attribute__((ext_vector_type(16))) float f32x16;

__device__ inline unsigned short f2bf(float f) {
    unsigned u = __float_as_uint(f);
    return (unsigned short)((u + 0x7FFFu + ((u >> 16) & 1u)) >> 16);
}
__device__ inline float bf2f(unsigned short h) {
    return __uint_as_float(((unsigned)h) << 16);
}

// ---------------------------------------------------------------------------
// P0: collapsed filters, elementwise: one thread per (cls, n, k).
// Layout cm[(cls*NMEM+n)*64+k] == gid.
// ---------------------------------------------------------------------------
__global__ __launch_bounds__(256) void prep_cm(const float* __restrict__ mem,
                                               unsigned short* __restrict__ cmh,
                                               unsigned short* __restrict__ cml) {
    const int gid = blockIdx.x * 256 + threadIdx.x;   // 4*16384*64 = 2^22
    const int k = gid & 63, n = (gid >> 6) & (NMEM - 1), cls = gid >> 20;
    const int u = k >> 3, v = k & 7, er = cls >> 1, ec = cls & 1;
    const int i0 = 2 * u - er, j0 = 2 * v - ec;
    const float* mrow = mem + (size_t)n * MDIM;
    float s = 0.f;
    #pragma unroll
    for (int di = 0; di < 2; ++di) {
        const int i = i0 + di;
        if ((unsigned)i >= 15u) continue;
        #pragma unroll
        for (int dj = 0; dj < 2; ++dj) {
            const int j = j0 + dj;
            if ((unsigned)j >= 15u) continue;
            s += mrow[i * 15 + j];
        }
    }
    const unsigned short h = f2bf(s);
    cmh[gid] = h;
    cml[gid] = f2bf(s - bf2f(h));
}

// ---------------------------------------------------------------------------
// P1: hn[n] = 0.5*||mem_n||^2 (f32 for rescue) + packed bf16 hi/lo (hnb) for
// the GEMM-folded subtraction. One wave per n.
// ---------------------------------------------------------------------------
__global__ __launch_bounds__(256) void prep_hn(const float* __restrict__ mem,
                                               float* __restrict__ hn,
                                               unsigned int* __restrict__ hnb) {
    const int wave = threadIdx.x >> 6, lane = threadIdx.x & 63;
    const int n = blockIdx.x * 4 + wave;
    const float* mrow = mem + (size_t)n * MDIM;
    float s = 0.f;
    for (int t = lane; t < MDIM; t += 64) { const float v = mrow[t]; s += v * v; }
    #pragma unroll
    for (int m = 1; m < 64; m <<= 1) s += __shfl_xor(s, m);
    if (lane == 0) {
        const float h = 0.5f * s;
        hn[n] = h;
        const unsigned short hi = f2bf(h);
        const unsigned short lo = f2bf(h - bf2f(hi));
        hnb[n] = (unsigned)hi | ((unsigned)lo << 16);
    }
}

// ---------------------------------------------------------------------------
// P2: X (positions) in B-fragment layout: x[(ptile*4+ks)*2+g][lane32][8j].
// ---------------------------------------------------------------------------
__global__ __launch_bounds__(256) void prep_x(const float* __restrict__ img,
                                              unsigned short* __restrict__ xh,
                                              unsigned short* __restrict__ xl) {
    const int t = blockIdx.x * 256 + threadIdx.x;   // 144*4*2*32 = 36864
    const int nl = t & 31, g = (t >> 5) & 1, ks = (t >> 6) & 3, pt = t >> 8;
    const int pos = pt * 32 + nl;
    const int u = ks * 2 + g;
    bf16x8 h, l;
    if (pos < MCLS) {
        const int mr = pos / 67, mc = pos - mr * 67;
        const int r = mr - 5 + u;
        #pragma unroll
        for (int j = 0; j < 8; ++j) {
            const int c = mc - 5 + j;
            float v = 0.f;
            if ((unsigned)r < 64u && (unsigned)c < 64u) v = img[r * 64 + c];
            const unsigned short hb = f2bf(v);
            h[j] = (short)hb;
            l[j] = (short)f2bf(v - bf2f(hb));
        }
    } else {
        #pragma unroll
        for (int j = 0; j < 8; ++j) { h[j] = 0; l[j] = 0; }
    }
    *(bf16x8*)(xh + (size_t)t * 8) = h;
    *(bf16x8*)(xl + (size_t)t * 8) = l;
}

// ---------------------------------------------------------------------------
// K1: MFMA scoring, occupancy-tuned. Grid (256 nblk, 4 cls), 4 waves/block,
// __launch_bounds__(256,4) -> 4 waves/SIMD, grid exactly resident.
// A (64 n x 64 k, hi/lo) staged in XOR-swizzled LDS (shared by all 4 waves);
// -hn folded into the GEMM via an extra K-slice (A_ext=-hn hi/lo, B_ext=1).
// Per wave-iter (36 iters): 1 position tile, 8 B-frag loads, 26 MFMAs,
// max-with-id epilogue, 1 store.
// A/B frag: row=lane&31, k=(lane>>5)*8+j. C/D: col=lane&31,
// row=(r&3)+8*(r>>2)+4*(lane>>5)  [HW-verified].
// ---------------------------------------------------------------------------
__global__ __launch_bounds__(256, 4) void mfma_argmin_kernel(const unsigned short* __restrict__ cmh,
                                                             const unsigned short* __restrict__ cml,
                                                             const unsigned short* __restrict__ xh,
                                                             const unsigned short* __restrict__ xl,
                                                             const unsigned int* __restrict__ hnb,
                                                             float* __restrict__ pcv) {
    __shared__ unsigned short AsH[4096];   // [row*64 + (chunk^(row&7))*8 + j]
    __shared__ unsigned short AsL[4096];
    const int nblk = blockIdx.x, cls = blockIdx.y;
    const int t = threadIdx.x, wave = t >> 6, lane = t & 63;
    const int g = lane >> 5, nl = lane & 31, sw = nl & 7;

    // Stage A into swizzled LDS (once per block; rows shared by all waves).
    for (int idx = t; idx < 512; idx += 256) {
        const int r = idx >> 3, c = idx & 7;
        const size_t src = ((size_t)(cls * NMEM + nblk * 64 + r)) * 64 + c * 8;
        const int dst = r * 64 + ((c ^ (r & 7)) * 8);
        *(bf16x8*)(AsH + dst) = *(const bf16x8*)(cmh + src);
        *(bf16x8*)(AsL + dst) = *(const bf16x8*)(cml + src);
    }

    // A_ext (-hn hi/lo) and B_ext (1,1) fragments for the hn-folding K-slice.
    const unsigned int hp0 = hnb[nblk * 64 + nl];
    const unsigned int hp1 = hnb[nblk * 64 + 32 + nl];
    bf16x8 aext0 = {0,0,0,0,0,0,0,0}, aext1 = {0,0,0,0,0,0,0,0}, bext = {0,0,0,0,0,0,0,0};
    if (g == 0) {
        aext0[0] = (short)((hp0 & 0xFFFFu) ^ 0x8000u);
        aext0[1] = (short)(((hp0 >> 16) & 0xFFFFu) ^ 0x8000u);
        aext1[0] = (short)((hp1 & 0xFFFFu) ^ 0x8000u);
        aext1[1] = (short)(((hp1 >> 16) & 0xFFFFu) ^ 0x8000u);
        bext[0] = (short)0x3F80;   // bf16 1.0
        bext[1] = (short)0x3F80;
    }
    __syncthreads();

    const size_t obase = (size_t)(cls * NTILE + nblk * 2) * PPAD;

    for (int it = 0; it < 36; ++it) {
        const int pt = it * 4 + wave;
        bf16x8 bh[4], bl[4];
        #pragma unroll
        for (int ks = 0; ks < 4; ++ks) {
            const size_t xo = ((size_t)((pt * 4 + ks) * 2 + g)) * 256 + nl * 8;
            bh[ks] = *(const bf16x8*)(xh + xo);
            bl[ks] = *(const bf16x8*)(xl + xo);
        }

        f32x16 acc0 = {0.f,0.f,0.f,0.f,0.f,0.f,0.f,0.f,0.f,0.f,0.f,0.f,0.f,0.f,0.f,0.f};
        f32x16 acc1 = {0.f,0.f,0.f,0.f,0.f,0.f,0.f,0.f,0.f,0.f,0.f,0.f,0.f,0.f,0.f,0.f};

        #pragma unroll
        for (int ks = 0; ks < 4; ++ks) {
            const int sh = (((ks * 2 + g) ^ sw) * 8);
            const bf16x8 ah0 = *(const bf16x8*)(AsH + nl * 64 + sh);
            const bf16x8 al0 = *(const bf16x8*)(AsL + nl * 64 + sh);
            const bf16x8 ah1 = *(const bf16x8*)(AsH + (nl + 32) * 64 + sh);
            const bf16x8 al1 = *(const bf16x8*)(AsL + (nl + 32) * 64 + sh);
            acc0 = __builtin_amdgcn_mfma_f32_32x32x16_bf16(ah0, bh[ks], acc0, 0, 0, 0);
            acc0 = __builtin_amdgcn_mfma_f32_32x32x16_bf16(al0, bh[ks], acc0, 0, 0, 0);
            acc0 = __builtin_amdgcn_mfma_f32_32x32x16_bf16(ah0, bl[ks], acc0, 0, 0, 0);
            acc1 = __builtin_amdgcn_mfma_f32_32x32x16_bf16(ah1, bh[ks], acc1, 0, 0, 0);
            acc1 = __builtin_amdgcn_mfma_f32_32x32x16_bf16(al1, bh[ks], acc1, 0, 0, 0);
            acc1 = __builtin_amdgcn_mfma_f32_32x32x16_bf16(ah1, bl[ks], acc1, 0, 0, 0);
        }
        acc0 = __builtin_amdgcn_mfma_f32_32x32x16_bf16(aext0, bext, acc0, 0, 0, 0);
        acc1 = __builtin_amdgcn_mfma_f32_32x32x16_bf16(aext1, bext, acc1, 0, 0, 0);

        // Epilogue: max over 32 n-rows with 5-bit row id packed in mantissa LSBs.
        float pm0 = -3.0e38f, pm1 = -3.0e38f;
        #pragma unroll
        for (int r = 0; r < 16; ++r) {
            const int id = (r & 3) + 8 * (r >> 2) + 4 * g;
            pm0 = fmaxf(pm0, __int_as_float((__float_as_int(acc0[r]) & ~31) | id));
            pm1 = fmaxf(pm1, __int_as_float((__float_as_int(acc1[r]) & ~31) | id));
        }
        pm0 = fmaxf(pm0, __shfl_xor(pm0, 32));
        pm1 = fmaxf(pm1, __shfl_xor(pm1, 32));

        const int pos = pt * 32 + nl;
        pcv[obase + (size_t)g * PPAD + pos] = g ? pm1 : pm0;
    }
}

// ---------------------------------------------------------------------------
// T: transpose pcv (4, NTILE, PPAD) -> pcvT (4, PPAD, NTILE), float4 both
// global sides, 64x64 LDS tile. Grid (PPAD/64, NTILE/64, 4).
// ---------------------------------------------------------------------------
__global__ __launch_bounds__(256) void transpose_kernel(const float* __restrict__ in,
                                                        float* __restrict__ out) {
    __shared__ float tile[64][65];
    const int pb = blockIdx.x, tb = blockIdx.y, cls = blockIdx.z;
    const int t = threadIdx.x;
    const int c4 = t & 15, r0 = t >> 4;
    #pragma unroll
    for (int rr = 0; rr < 4; ++rr) {
        const int row = r0 + rr * 16;
        const float4 v = *(const float4*)(in + ((size_t)(cls * NTILE + tb * 64 + row)) * PPAD + pb * 64 + c4 * 4);
        tile[row][c4 * 4 + 0] = v.x;
        tile[row][c4 * 4 + 1] = v.y;
        tile[row][c4 * 4 + 2] = v.z;
        tile[row][c4 * 4 + 3] = v.w;
    }
    __syncthreads();
    #pragma unroll
    for (int rr = 0; rr < 4; ++rr) {
        const int p = r0 + rr * 16;
        float4 v;
        v.x = tile[c4 * 4 + 0][p];
        v.y = tile[c4 * 4 + 1][p];
        v.z = tile[c4 * 4 + 2][p];
        v.w = tile[c4 * 4 + 3][p];
        *(float4*)(out + ((size_t)(cls * PPAD + pb * 64 + p)) * NTILE + tb * 64 + c4 * 4) = v;
    }
}

// ---------------------------------------------------------------------------
// K2: rescue, one wave per (cls, pos): coalesced read of 512 tile-maxes,
// shfl-max vmax, ballot candidates within MARGIN, wave-cooperative exact
// rescore. Tie rule matches argmin-first.
// ---------------------------------------------------------------------------
__global__ __launch_bounds__(256) void rescue_kernel(const float* __restrict__ img,
                                                     const float* __restrict__ mem,
                                                     const float* __restrict__ hn,
                                                     const float* __restrict__ pcvT,
                                                     int* __restrict__ idx2d) {
    const int wave = threadIdx.x >> 6, lane = threadIdx.x & 63;
    const int cls = blockIdx.y;
    const int pos = blockIdx.x * 4 + wave;
    if (pos >= MCLS) return;
    const int er = cls >> 1, ec = cls & 1;
    const int mr = pos / 67, mc = pos - mr * 67;

    const int xr = mr - 5 + (lane >> 3), xc = mc - 5 + (lane & 7);
    const float xv = ((unsigned)xr < 64u && (unsigned)xc < 64u) ? img[xr * 64 + xc] : 0.f;

    float xt[4];
    #pragma unroll
    for (int q = 0; q < 4; ++q) {
        const int tt = q * 64 + lane;
        const int a = tt / 15, b = tt - 15 * a;
        const int xi = (((a + er) >> 1) & 7) * 8 + (((b + ec) >> 1) & 7);
        xt[q] = __shfl(xv, xi);
    }

    const float* row = pcvT + ((size_t)(cls * PPAD + pos)) * NTILE + lane * 8;
    const float4 v0 = *(const float4*)row;
    const float4 v1 = *(const float4*)(row + 4);
    float vals[8] = {v0.x, v0.y, v0.z, v0.w, v1.x, v1.y, v1.z, v1.w};

    float vmax = vals[0];
    #pragma unroll
    for (int s = 1; s < 8; ++s) vmax = fmaxf(vmax, vals[s]);
    #pragma unroll
    for (int m = 1; m < 64; m <<= 1) vmax = fmaxf(vmax, __shfl_xor(vmax, m));
    const float thr = vmax - MARGIN;

    float best = -3.0e38f; int bn = 0x7FFFFFFF;
    #pragma unroll
    for (int s = 0; s < 8; ++s) {
        unsigned long long bal = __ballot(vals[s] >= thr);
        while (bal) {
            const int src = __ffsll((long long)bal) - 1;
            bal &= bal - 1;
            const float pv = __shfl(vals[s], src);
            const int n = (src * 8 + s) * 32 + (__float_as_int(pv) & 31);
            const float* mrow = mem + (size_t)n * MDIM;
            float part = 0.f;
            #pragma unroll
            for (int q = 0; q < 4; ++q) {
                const int tt = q * 64 + lane;
                if (tt < MDIM) part = fmaf(mrow[tt], xt[q], part);
            }
            #pragma unroll
            for (int m = 1; m < 64; m <<= 1) part += __shfl_xor(part, m);
            const float sc = part - hn[n];
            if (sc > best || (sc == best && n < bn)) { best = sc; bn = n; }
        }
    }
    if (lane == 0) idx2d[(er + 2 * mr) * L1D + (ec + 2 * mc)] = bn;
}

// ---------------------------------------------------------------------------
// K3: fold, one wave per output pixel.
// ---------------------------------------------------------------------------
__global__ __launch_bounds__(256) void fold_kernel(const float* __restrict__ mem,
                                                   const int* __restrict__ idx2d,
                                                   float* __restrict__ outraw) {
    const int wave = threadIdx.x >> 6, lane = threadIdx.x & 63;
    const int p = blockIdx.x * 4 + wave;   // 0..4095
    const int oi = p >> 6, oj = p & 63;
    float s = 0.f;
    #pragma unroll
    for (int tb = 0; tb < 256; tb += 64) {
        const int tt = tb + lane;
        if (tt < MDIM) {
            const int a = tt / 15, b = tt - 15 * a;
            const int r = 10 + 2 * oi - a, c = 10 + 2 * oj - b;
            if ((unsigned)r < (unsigned)L1D && (unsigned)c < (unsigned)L1D) {
                const int n = idx2d[r * L1D + c];
                s += mem[(size_t)n * MDIM + tt];
            }
        }
    }
    #pragma unroll
    for (int msk = 1; msk < 64; msk <<= 1) s += __shfl_xor(s, msk);
    if (lane == 0) outraw[p] = s;
}

// ---------------------------------------------------------------------------
// K4: divide by global max (single block).
// ---------------------------------------------------------------------------
__global__ __launch_bounds__(256) void norm_kernel(const float* __restrict__ outraw,
                                                   float* __restrict__ out) {
    __shared__ float red[256];
    const int t = threadIdx.x;
    float m = -3.0e38f;
    #pragma unroll
    for (int i = 0; i < 16; ++i) m = fmaxf(m, outraw[t + i * 256]);
    red[t] = m;
    __syncthreads();
    for (int s = 128; s > 0; s >>= 1) {
        if (t < s) red[t] = fmaxf(red[t], red[t + s]);
        __syncthreads();
    }
    const float mx = red[0];
    #pragma unroll
    for (int i = 0; i < 16; ++i) out[t + i * 256] = outraw[t + i * 256] / mx;
}

extern "C" void kernel_launch(void* const* d_in, const int* in_sizes, int n_in,
                              void* d_out, int out_size, void* d_ws, size_t ws_size,
                              hipStream_t stream) {
    const float* img = (const float*)d_in[0];   // 64*64 fp32
    const float* mem = (const float*)d_in[1];   // 16384*225 fp32
    float* out = (float*)d_out;                 // 4096 fp32

    unsigned short* cmh = (unsigned short*)d_ws;              // 4*16384*64 shorts
    unsigned short* cml = cmh + (size_t)4 * NMEM * 64;
    float* hn = (float*)(cml + (size_t)4 * NMEM * 64);        // 16384 f
    unsigned int* hnb = (unsigned int*)(hn + NMEM);           // 16384 u32
    unsigned short* xh = (unsigned short*)(hnb + NMEM);       // 294912 shorts
    unsigned short* xl = xh + 294912;
    float* pcv = (float*)(xl + 294912);                       // 4*512*4608 f = 37.7 MB
    float* pcvT = pcv + (size_t)4 * NTILE * PPAD;             // 37.7 MB
    int* idx2d = (int*)(pcvT + (size_t)4 * NTILE * PPAD);     // 17956 i
    float* outraw = (float*)(idx2d + L1D * L1D);              // 4096 f

    prep_cm<<<(4 * NMEM * 64) / 256, 256, 0, stream>>>(mem, cmh, cml);
    prep_hn<<<NMEM / 4, 256, 0, stream>>>(mem, hn, hnb);
    prep_x<<<144, 256, 0, stream>>>(img, xh, xl);
    mfma_argmin_kernel<<<dim3(256, 4), 256, 0, stream>>>(cmh, cml, xh, xl, hnb, pcv);
    transpose_kernel<<<dim3(PPAD / 64, NTILE / 64, 4), 256, 0, stream>>>(pcv, pcvT);
    rescue_kernel<<<dim3((MCLS + 3) / 4, 4), 256, 0, stream>>>(img, mem, hn, pcvT, idx2d);
    fold_kernel<<<1024, 256, 0, stream>>>(mem, idx2d, outraw);
    norm_kernel<<<1, 256, 0, stream>>>(outraw, out);
}

// Round 8
// 175.094 us; speedup vs baseline: 4.1508x; 1.3363x over previous
//
#include <hip/hip_runtime.h>

#define NMEM 16384
#define MDIM 225
#define L1D 134
#define MCLS 4489     // 67*67 real positions per class
#define PPAD 4608     // 144*32 padded positions
#define NTILE2 512    // 256 tiles * 2 surfaced candidates
#define MARGIN 0.5f

typedef __attribute__((ext_vector_type(8))) _Float16 f16x8;
typedef __attribute__((ext_vector_type(16))) float f32x16;

__device__ inline unsigned short f2h(float f) {
    const _Float16 h = (_Float16)f;
    unsigned short u; __builtin_memcpy(&u, &h, 2); return u;
}
__device__ inline _Float16 us2h(unsigned short u) {
    _Float16 h; __builtin_memcpy(&h, &u, 2); return h;
}
__device__ inline float h2f(unsigned short u) { return (float)us2h(u); }

// ---------------------------------------------------------------------------
// P0: collapsed filters -> fp16. One thread per (cls, n, k); cmh[gid].
// ---------------------------------------------------------------------------
__global__ __launch_bounds__(256) void prep_cm(const float* __restrict__ mem,
                                               unsigned short* __restrict__ cmh) {
    const int gid = blockIdx.x * 256 + threadIdx.x;   // 4*16384*64 = 2^22
    const int k = gid & 63, n = (gid >> 6) & (NMEM - 1), cls = gid >> 20;
    const int u = k >> 3, v = k & 7, er = cls >> 1, ec = cls & 1;
    const int i0 = 2 * u - er, j0 = 2 * v - ec;
    const float* mrow = mem + (size_t)n * MDIM;
    float s = 0.f;
    #pragma unroll
    for (int di = 0; di < 2; ++di) {
        const int i = i0 + di;
        if ((unsigned)i >= 15u) continue;
        #pragma unroll
        for (int dj = 0; dj < 2; ++dj) {
            const int j = j0 + dj;
            if ((unsigned)j >= 15u) continue;
            s += mrow[i * 15 + j];
        }
    }
    cmh[gid] = f2h(s);
}

// ---------------------------------------------------------------------------
// P1: hn[n] = 0.5*||mem_n||^2 (f32 for rescue) + packed fp16 (-hn_hi,-hn_lo)
// for the GEMM-folded subtraction. One wave per n.
// ---------------------------------------------------------------------------
__global__ __launch_bounds__(256) void prep_hn(const float* __restrict__ mem,
                                               float* __restrict__ hn,
                                               unsigned int* __restrict__ hnb) {
    const int wave = threadIdx.x >> 6, lane = threadIdx.x & 63;
    const int n = blockIdx.x * 4 + wave;
    const float* mrow = mem + (size_t)n * MDIM;
    float s = 0.f;
    for (int t = lane; t < MDIM; t += 64) { const float v = mrow[t]; s += v * v; }
    #pragma unroll
    for (int m = 1; m < 64; m <<= 1) s += __shfl_xor(s, m);
    if (lane == 0) {
        const float h = 0.5f * s;
        hn[n] = h;
        const unsigned short nh = f2h(-h);
        const unsigned short nl = f2h(-h - h2f(nh));
        hnb[n] = (unsigned)nh | ((unsigned)nl << 16);
    }
}

// ---------------------------------------------------------------------------
// P2: X (positions) in B-fragment layout, fp16: x[(pt*4+ks)*2+g][lane32][8j].
// ---------------------------------------------------------------------------
__global__ __launch_bounds__(256) void prep_x(const float* __restrict__ img,
                                              unsigned short* __restrict__ xh) {
    const int t = blockIdx.x * 256 + threadIdx.x;   // 144*4*2*32 = 36864
    const int nl = t & 31, g = (t >> 5) & 1, ks = (t >> 6) & 3, pt = t >> 8;
    const int pos = pt * 32 + nl;
    const int u = ks * 2 + g;
    unsigned short h[8];
    if (pos < MCLS) {
        const int mr = pos / 67, mc = pos - mr * 67;
        const int r = mr - 5 + u;
        #pragma unroll
        for (int j = 0; j < 8; ++j) {
            const int c = mc - 5 + j;
            float v = 0.f;
            if ((unsigned)r < 64u && (unsigned)c < 64u) v = img[r * 64 + c];
            h[j] = f2h(v);
        }
    } else {
        #pragma unroll
        for (int j = 0; j < 8; ++j) h[j] = 0;
    }
    #pragma unroll
    for (int j = 0; j < 8; ++j) xh[(size_t)t * 8 + j] = h[j];
}

// ---------------------------------------------------------------------------
// K1: fp16 single-product MFMA scoring. Grid (256 nblk, 4 cls), 4 waves,
// __launch_bounds__(256,4). A (64 n x 64 k) register-resident; -hn folded via
// fp16 hi/lo ext K-slice. B double-buffered in registers. No LDS, no barriers.
// Per-iter B stride: one position-tile = 4ks*2g*256 = 2048 halves; a wave's
// pt advances by 4 tiles/iter => xp += 8192.   (R6/R7 bug: advanced 2048.)
// Epilogue: TOP-2 over 64 n (6-bit id in mantissa LSBs), stored directly in
// transposed layout pcvT[(cls*PPAD+pos)*512 + nblk*2 + {0,1}] (8B scatter).
// A/B frag: row=lane&31, k=(lane>>5)*8+j. C/D: col=lane&31,
// row=(r&3)+8*(r>>2)+4*(lane>>5)  [HW-verified].
// ---------------------------------------------------------------------------
__global__ __launch_bounds__(256, 4) void mfma_argmin_kernel(const unsigned short* __restrict__ cmh,
                                                             const unsigned short* __restrict__ xh,
                                                             const unsigned int* __restrict__ hnb,
                                                             float* __restrict__ pcvT) {
    const int nblk = blockIdx.x, cls = blockIdx.y;
    const int t = threadIdx.x, wave = t >> 6, lane = t & 63;
    const int g = lane >> 5, nl = lane & 31;

    // One-time A fragment loads (row nl and nl+32, all 4 K-slices).
    f16x8 a0[4], a1[4];
    #pragma unroll
    for (int ks = 0; ks < 4; ++ks) {
        const size_t base = ((size_t)(cls * NMEM + nblk * 64 + nl)) * 64 + ks * 16 + g * 8;
        a0[ks] = *(const f16x8*)(cmh + base);
        a1[ks] = *(const f16x8*)(cmh + base + 32 * 64);
    }

    // hn-folding ext slice: A_ext=(-hn_hi,-hn_lo,0..), B_ext=(1,1,0..).
    const unsigned int hp0 = hnb[nblk * 64 + nl];
    const unsigned int hp1 = hnb[nblk * 64 + 32 + nl];
    f16x8 aex0 = {0,0,0,0,0,0,0,0}, aex1 = {0,0,0,0,0,0,0,0}, bex = {0,0,0,0,0,0,0,0};
    if (g == 0) {
        aex0[0] = us2h((unsigned short)(hp0 & 0xFFFFu));
        aex0[1] = us2h((unsigned short)(hp0 >> 16));
        aex1[0] = us2h((unsigned short)(hp1 & 0xFFFFu));
        aex1[1] = us2h((unsigned short)(hp1 >> 16));
        bex[0] = (_Float16)1.0f;
        bex[1] = (_Float16)1.0f;
    }

    // B pointer for this wave/g: pt = it*4+wave  =>  +8192 halves per iter.
    const unsigned short* xp = xh + ((size_t)((wave * 4) * 2 + g)) * 256 + nl * 8;

    f16x8 bcur[4], bnxt[4];
    #pragma unroll
    for (int ks = 0; ks < 4; ++ks) bcur[ks] = *(const f16x8*)(xp + ks * 512);

    for (int it = 0; it < 36; ++it) {
        if (it < 35) {
            const unsigned short* xn = xp + 8192;
            #pragma unroll
            for (int ks = 0; ks < 4; ++ks) bnxt[ks] = *(const f16x8*)(xn + ks * 512);
        }

        f32x16 acc0 = {0.f,0.f,0.f,0.f,0.f,0.f,0.f,0.f,0.f,0.f,0.f,0.f,0.f,0.f,0.f,0.f};
        f32x16 acc1 = {0.f,0.f,0.f,0.f,0.f,0.f,0.f,0.f,0.f,0.f,0.f,0.f,0.f,0.f,0.f,0.f};
        #pragma unroll
        for (int ks = 0; ks < 4; ++ks) {
            acc0 = __builtin_amdgcn_mfma_f32_32x32x16_f16(a0[ks], bcur[ks], acc0, 0, 0, 0);
            acc1 = __builtin_amdgcn_mfma_f32_32x32x16_f16(a1[ks], bcur[ks], acc1, 0, 0, 0);
        }
        acc0 = __builtin_amdgcn_mfma_f32_32x32x16_f16(aex0, bex, acc0, 0, 0, 0);
        acc1 = __builtin_amdgcn_mfma_f32_32x32x16_f16(aex1, bex, acc1, 0, 0, 0);

        // Epilogue: TOP-2 over 64 n, 6-bit id packed in mantissa LSBs.
        float m1 = -3.0e38f, m2 = -3.0e38f;
        #pragma unroll
        for (int r = 0; r < 16; ++r) {
            const int id = (r & 3) + 8 * (r >> 2) + 4 * g;
            float v = __int_as_float((__float_as_int(acc0[r]) & ~63) | id);
            m2 = fmaxf(m2, fminf(m1, v)); m1 = fmaxf(m1, v);
            v = __int_as_float((__float_as_int(acc1[r]) & ~63) | (id + 32));
            m2 = fmaxf(m2, fminf(m1, v)); m1 = fmaxf(m1, v);
        }
        const float o1 = __shfl_xor(m1, 32);
        const float o2 = __shfl_xor(m2, 32);
        const float M1 = fmaxf(m1, o1);
        const float M2 = fmaxf(fminf(m1, o1), fmaxf(m2, o2));

        if (g == 0) {
            const int pos = (it * 4 + wave) * 32 + nl;
            float2 st; st.x = M1; st.y = M2;
            *(float2*)(pcvT + ((size_t)(cls * PPAD + pos)) * NTILE2 + nblk * 2) = st;
        }

        xp += 8192;
        #pragma unroll
        for (int ks = 0; ks < 4; ++ks) bcur[ks] = bnxt[ks];
    }
}

// ---------------------------------------------------------------------------
// K2: rescue, one wave per (cls, pos): coalesced read of 512 surfaced
// candidates (256 tiles x top-2), shfl-max vmax, ballot candidates within
// MARGIN, wave-cooperative exact fp32 rescore from mem. Tie rule matches
// argmin-first.
// ---------------------------------------------------------------------------
__global__ __launch_bounds__(256) void rescue_kernel(const float* __restrict__ img,
                                                     const float* __restrict__ mem,
                                                     const float* __restrict__ hn,
                                                     const float* __restrict__ pcvT,
                                                     int* __restrict__ idx2d) {
    const int wave = threadIdx.x >> 6, lane = threadIdx.x & 63;
    const int cls = blockIdx.y;
    const int pos = blockIdx.x * 4 + wave;
    if (pos >= MCLS) return;
    const int er = cls >> 1, ec = cls & 1;
    const int mr = pos / 67, mc = pos - mr * 67;

    const int xr = mr - 5 + (lane >> 3), xc = mc - 5 + (lane & 7);
    const float xv = ((unsigned)xr < 64u && (unsigned)xc < 64u) ? img[xr * 64 + xc] : 0.f;

    float xt[4];
    #pragma unroll
    for (int q = 0; q < 4; ++q) {
        const int tt = q * 64 + lane;
        const int a = tt / 15, b = tt - 15 * a;
        const int xi = (((a + er) >> 1) & 7) * 8 + (((b + ec) >> 1) & 7);
        xt[q] = __shfl(xv, xi);
    }

    const float* row = pcvT + ((size_t)(cls * PPAD + pos)) * NTILE2 + lane * 8;
    const float4 v0 = *(const float4*)row;
    const float4 v1 = *(const float4*)(row + 4);
    float vals[8] = {v0.x, v0.y, v0.z, v0.w, v1.x, v1.y, v1.z, v1.w};

    float vmax = vals[0];
    #pragma unroll
    for (int s = 1; s < 8; ++s) vmax = fmaxf(vmax, vals[s]);
    #pragma unroll
    for (int m = 1; m < 64; m <<= 1) vmax = fmaxf(vmax, __shfl_xor(vmax, m));
    const float thr = vmax - MARGIN;

    float best = -3.0e38f; int bn = 0x7FFFFFFF;
    #pragma unroll
    for (int s = 0; s < 8; ++s) {
        unsigned long long bal = __ballot(vals[s] >= thr);
        while (bal) {
            const int src = __ffsll((long long)bal) - 1;
            bal &= bal - 1;
            const float pv = __shfl(vals[s], src);
            const int e = src * 8 + s;                       // entry 0..511
            const int n = ((e >> 1) << 6) | (__float_as_int(pv) & 63);
            const float* mrow = mem + (size_t)n * MDIM;
            float part = 0.f;
            #pragma unroll
            for (int q = 0; q < 4; ++q) {
                const int tt = q * 64 + lane;
                if (tt < MDIM) part = fmaf(mrow[tt], xt[q], part);
            }
            #pragma unroll
            for (int m = 1; m < 64; m <<= 1) part += __shfl_xor(part, m);
            const float sc = part - hn[n];
            if (sc > best || (sc == best && n < bn)) { best = sc; bn = n; }
        }
    }
    if (lane == 0) idx2d[(er + 2 * mr) * L1D + (ec + 2 * mc)] = bn;
}

// ---------------------------------------------------------------------------
// K3: fold, one wave per output pixel.
// ---------------------------------------------------------------------------
__global__ __launch_bounds__(256) void fold_kernel(const float* __restrict__ mem,
                                                   const int* __restrict__ idx2d,
                                                   float* __restrict__ outraw) {
    const int wave = threadIdx.x >> 6, lane = threadIdx.x & 63;
    const int p = blockIdx.x * 4 + wave;   // 0..4095
    const int oi = p >> 6, oj = p & 63;
    float s = 0.f;
    #pragma unroll
    for (int tb = 0; tb < 256; tb += 64) {
        const int tt = tb + lane;
        if (tt < MDIM) {
            const int a = tt / 15, b = tt - 15 * a;
            const int r = 10 + 2 * oi - a, c = 10 + 2 * oj - b;
            if ((unsigned)r < (unsigned)L1D && (unsigned)c < (unsigned)L1D) {
                const int n = idx2d[r * L1D + c];
                s += mem[(size_t)n * MDIM + tt];
            }
        }
    }
    #pragma unroll
    for (int msk = 1; msk < 64; msk <<= 1) s += __shfl_xor(s, msk);
    if (lane == 0) outraw[p] = s;
}

// ---------------------------------------------------------------------------
// K4: divide by global max (single block).
// ---------------------------------------------------------------------------
__global__ __launch_bounds__(256) void norm_kernel(const float* __restrict__ outraw,
                                                   float* __restrict__ out) {
    __shared__ float red[256];
    const int t = threadIdx.x;
    float m = -3.0e38f;
    #pragma unroll
    for (int i = 0; i < 16; ++i) m = fmaxf(m, outraw[t + i * 256]);
    red[t] = m;
    __syncthreads();
    for (int s = 128; s > 0; s >>= 1) {
        if (t < s) red[t] = fmaxf(red[t], red[t + s]);
        __syncthreads();
    }
    const float mx = red[0];
    #pragma unroll
    for (int i = 0; i < 16; ++i) out[t + i * 256] = outraw[t + i * 256] / mx;
}

extern "C" void kernel_launch(void* const* d_in, const int* in_sizes, int n_in,
                              void* d_out, int out_size, void* d_ws, size_t ws_size,
                              hipStream_t stream) {
    const float* img = (const float*)d_in[0];   // 64*64 fp32
    const float* mem = (const float*)d_in[1];   // 16384*225 fp32
    float* out = (float*)d_out;                 // 4096 fp32

    unsigned short* cmh = (unsigned short*)d_ws;              // 4*16384*64 ushort = 8.4 MB
    float* hn = (float*)(cmh + (size_t)4 * NMEM * 64);        // 16384 f
    unsigned int* hnb = (unsigned int*)(hn + NMEM);           // 16384 u32
    unsigned short* xh = (unsigned short*)(hnb + NMEM);       // 294912 ushort
    float* pcvT = (float*)(xh + 294912);                      // 4*4608*512 f = 37.7 MB
    int* idx2d = (int*)(pcvT + (size_t)4 * PPAD * NTILE2);    // 17956 i
    float* outraw = (float*)(idx2d + L1D * L1D);              // 4096 f

    prep_cm<<<(4 * NMEM * 64) / 256, 256, 0, stream>>>(mem, cmh);
    prep_hn<<<NMEM / 4, 256, 0, stream>>>(mem, hn, hnb);
    prep_x<<<144, 256, 0, stream>>>(img, xh);
    mfma_argmin_kernel<<<dim3(256, 4), 256, 0, stream>>>(cmh, xh, hnb, pcvT);
    rescue_kernel<<<dim3((MCLS + 3) / 4, 4), 256, 0, stream>>>(img, mem, hn, pcvT, idx2d);
    fold_kernel<<<1024, 256, 0, stream>>>(mem, idx2d, outraw);
    norm_kernel<<<1, 256, 0, stream>>>(outraw, out);
}